// Round 8
// baseline (642.567 us; speedup 1.0000x reference)
//
#include <hip/hip_runtime.h>

#define BB 2
#define NN 32768
#define KK 16
#define DD 64
#define NC 10
#define NMOM 65
#define NBLK1 256
#define BN_EPS 1e-6
#define BNK ((size_t)BB * NN * KK)   // 1,048,576 elements per c-channel

__host__ __device__ __forceinline__ constexpr int pair_idx(int i, int j) {
    return 10 + i * 10 - (i * (i - 1)) / 2 + (j - i);
}

// ---------------- Kernel 1: concat-vector moment reduction ----------------
__global__ __launch_bounds__(256) void k_moments(
    const float* __restrict__ coords, const float* __restrict__ dist,
    const int* __restrict__ idx, float* __restrict__ partials)
{
    const int tid = threadIdx.x;
    const int bn = blockIdx.x * 256 + tid;
    const int b = bn >> 15;

    float acc[NMOM];
#pragma unroll
    for (int v = 0; v < NMOM; ++v) acc[v] = 0.f;

    const float cx = coords[(size_t)bn * 3 + 0];
    const float cy = coords[(size_t)bn * 3 + 1];
    const float cz = coords[(size_t)bn * 3 + 2];
    const float* cb = coords + (size_t)b * NN * 3;

    for (int k = 0; k < KK; ++k) {
        const int j = idx[(size_t)bn * KK + k];
        const float nx = cb[(size_t)j * 3 + 0];
        const float ny = cb[(size_t)j * 3 + 1];
        const float nz = cb[(size_t)j * 3 + 2];
        const float dd = dist[(size_t)bn * KK + k];
        const float c[NC] = {cx, cy, cz, nx, ny, nz, cx - nx, cy - ny, cz - nz, dd};
#pragma unroll
        for (int i = 0; i < NC; ++i) acc[i] += c[i];
#pragma unroll
        for (int i = 0; i < NC; ++i)
#pragma unroll
            for (int jj = i; jj < NC; ++jj)
                acc[pair_idx(i, jj)] += c[i] * c[jj];
    }

    __shared__ float red[4 * NMOM];
    const int lane = tid & 63, wave = tid >> 6;
#pragma unroll
    for (int v = 0; v < NMOM; ++v) {
        float x = acc[v];
        x += __shfl_down(x, 32);
        x += __shfl_down(x, 16);
        x += __shfl_down(x, 8);
        x += __shfl_down(x, 4);
        x += __shfl_down(x, 2);
        x += __shfl_down(x, 1);
        if (lane == 0) red[wave * NMOM + v] = x;
    }
    __syncthreads();
    if (tid < NMOM) {
        float p = red[tid] + red[NMOM + tid] + red[2 * NMOM + tid] + red[3 * NMOM + tid];
        partials[blockIdx.x * NMOM + tid] = p;
    }
}

// ---------------- Kernel 2: finalize BN stats, fold into w/bias ----------------
__global__ __launch_bounds__(320) void k_finalize(
    const float* __restrict__ partials,
    const float* __restrict__ conv_w, const float* __restrict__ conv_b,
    const float* __restrict__ gamma, const float* __restrict__ beta,
    float* __restrict__ wscaled, float* __restrict__ bias2)
{
    __shared__ double part[4][NMOM];
    __shared__ double sums[NMOM];
    const int tid = threadIdx.x;
    const int g = tid / NMOM, m = tid % NMOM;
    if (g < 4) {
        double s = 0.0;
        for (int blk = g * 64; blk < (g + 1) * 64; ++blk)
            s += (double)partials[blk * NMOM + m];
        part[g][m] = s;
    }
    __syncthreads();
    if (tid < NMOM)
        sums[tid] = part[0][tid] + part[1][tid] + part[2][tid] + part[3][tid];
    __syncthreads();
    if (tid < DD) {
        const double cnt = (double)BB * NN * KK;
        double mm[NC], w[NC];
#pragma unroll
        for (int c = 0; c < NC; ++c) {
            mm[c] = sums[c] / cnt;
            w[c] = (double)conv_w[tid * NC + c];
        }
        const double bd = (double)conv_b[tid];
        double wm = 0.0;
#pragma unroll
        for (int c = 0; c < NC; ++c) wm += w[c] * mm[c];
        const double mean = wm + bd;
        double ex2 = bd * bd + 2.0 * bd * wm;
#pragma unroll
        for (int i = 0; i < NC; ++i)
#pragma unroll
            for (int j = i; j < NC; ++j) {
                const double Mij = sums[pair_idx(i, j)] / cnt;
                ex2 += (i == j ? 1.0 : 2.0) * w[i] * w[j] * Mij;
            }
        const double var = ex2 - mean * mean;
        const double scale = (double)gamma[tid] / sqrt(var + BN_EPS);
        bias2[tid] = (float)((double)beta[tid] + (bd - mean) * scale);
#pragma unroll
        for (int c = 0; c < NC; ++c)
            wscaled[tid * NC + c] = (float)(w[c] * scale);
    }
}

// ---------------- Kernel 3: stage c-vectors once, transposed [ch][bnk] ------
// thread = (bn, k-quad): gathers 4 neighbors, writes one float4 per channel.
__global__ __launch_bounds__(256) void k_c(
    const float* __restrict__ coords, const float* __restrict__ dist,
    const int* __restrict__ idx, float* __restrict__ cbuf)
{
    const int t = blockIdx.x * 256 + threadIdx.x;   // 0 .. BNK/4 - 1
    const int e0 = t << 2;
    const int bn = e0 >> 4;
    const int k0 = e0 & 15;
    const int b = bn >> 15;

    const float* cc = coords + (size_t)bn * 3;
    const float cx = cc[0], cy = cc[1], cz = cc[2];
    const float* cb = coords + (size_t)b * NN * 3;

    const int4 j4 = *reinterpret_cast<const int4*>(idx + (size_t)bn * KK + k0);
    const float4 d4 = *reinterpret_cast<const float4*>(dist + (size_t)bn * KK + k0);
    const int js[4] = {j4.x, j4.y, j4.z, j4.w};
    const float dsv[4] = {d4.x, d4.y, d4.z, d4.w};

    float c[4][NC];
#pragma unroll
    for (int q = 0; q < 4; ++q) {
        const float* nc2 = cb + (size_t)js[q] * 3;
        const float nx = nc2[0], ny = nc2[1], nz = nc2[2];
        c[q][0] = cx; c[q][1] = cy; c[q][2] = cz;
        c[q][3] = nx; c[q][4] = ny; c[q][5] = nz;
        c[q][6] = cx - nx; c[q][7] = cy - ny; c[q][8] = cz - nz;
        c[q][9] = dsv[q];
    }
#pragma unroll
    for (int ch = 0; ch < NC; ++ch) {
        float4 v{c[0][ch], c[1][ch], c[2][ch], c[3][ch]};
        *reinterpret_cast<float4*>(&cbuf[(size_t)ch * BNK + e0]) = v;
    }
}

// ---------------- Kernel 4: single monotonic write front over all 512 MiB ---
// Block = one contiguous 16 KiB output chunk: (b, ch2, nc), nc FASTEST so
// blockIdx is monotonic in output address (k_feat-like). x-half blocks read
// staged c coalesced and apply 10 block-uniform FMAs; feat-half broadcasts.
__global__ __launch_bounds__(256) void k_out(
    const float* __restrict__ cbuf, const float* __restrict__ features,
    const float* __restrict__ wscaled, const float* __restrict__ bias2,
    float* __restrict__ out)
{
    const int nc  = blockIdx.x & 127;            // 128 chunks of 256 n
    const int ch2 = (blockIdx.x >> 7) & 127;
    const int b   = blockIdx.x >> 14;
    const int tid = threadIdx.x;
    const size_t plane = ((size_t)b * 2 * DD + ch2) * ((size_t)NN * KK);

    if (ch2 < DD) {
        const int d = ch2;                        // block-uniform -> s_loads
        float wv[NC];
#pragma unroll
        for (int ch = 0; ch < NC; ++ch) wv[ch] = wscaled[d * NC + ch];
        const float b2 = bias2[d];
        const size_t locbase = (size_t)nc * 256 * KK;        // within-plane
        const size_t ebase = (size_t)b * NN * KK + locbase;  // within c-channel

#pragma unroll
        for (int j = 0; j < 4; ++j) {
            const size_t off = (size_t)(j * 1024 + tid * 4); // dense per instr
            float4 a{b2, b2, b2, b2};
#pragma unroll
            for (int ch = 0; ch < NC; ++ch) {
                const float4 cv = *reinterpret_cast<const float4*>(
                    &cbuf[(size_t)ch * BNK + ebase + off]);
                const float w = wv[ch];
                a.x += cv.x * w; a.y += cv.y * w;
                a.z += cv.z * w; a.w += cv.w * w;
            }
            a.x = fmaxf(a.x, 0.f); a.y = fmaxf(a.y, 0.f);
            a.z = fmaxf(a.z, 0.f); a.w = fmaxf(a.w, 0.f);
            *reinterpret_cast<float4*>(out + plane + locbase + off) = a;
        }
    } else {
        const int d = ch2 - DD;
        const float* fb = features + ((size_t)b * DD + d) * NN;
        const size_t locbase = (size_t)nc * 256 * KK;
#pragma unroll
        for (int j = 0; j < 4; ++j) {
            const int q = j * 256 + tid;          // float4 index in chunk
            const int n = nc * 256 + (q >> 2);    // 4 quads per n
            const float f = fb[n];
            *reinterpret_cast<float4*>(out + plane + locbase + (size_t)q * 4) =
                float4{f, f, f, f};
        }
    }
}

// ---------------- launch ----------------
extern "C" void kernel_launch(void* const* d_in, const int* in_sizes, int n_in,
                              void* d_out, int out_size, void* d_ws, size_t ws_size,
                              hipStream_t stream) {
    const float* coords   = (const float*)d_in[0];
    const float* features = (const float*)d_in[1];
    const float* dist     = (const float*)d_in[2];
    const float* conv_w   = (const float*)d_in[3];
    const float* conv_b   = (const float*)d_in[4];
    const float* gamma    = (const float*)d_in[5];
    const float* beta     = (const float*)d_in[6];
    const int*   idx      = (const int*)d_in[7];
    float* out = (float*)d_out;

    float* partials = (float*)d_ws;                 // 256*65 floats
    float* wscaled  = partials + NBLK1 * NMOM;      // 640 floats
    float* bias2    = wscaled + DD * NC;            // 64 floats
    float* cbuf     = (float*)d_ws + 65536;         // 10 * BNK floats = 40 MiB

    k_moments<<<NBLK1, 256, 0, stream>>>(coords, dist, idx, partials);
    k_finalize<<<1, 320, 0, stream>>>(partials, conv_w, conv_b, gamma, beta,
                                      wscaled, bias2);
    k_c<<<(int)(BNK / 4 / 256), 256, 0, stream>>>(coords, dist, idx, cbuf);
    k_out<<<BB * 128 * 128, 256, 0, stream>>>(cbuf, features, wscaled, bias2, out);
}